// Round 2
// baseline (1736.175 us; speedup 1.0000x reference)
//
#include <hip/hip_runtime.h>
#include <hip/hip_bf16.h>

#define BATCH 64
#define SEQT  2048
#define FEAT  64
#define HID   128
#define G4    512              // 4*HID
#define CHUNK 16
#define NCHUNK (SEQT / CHUNK)  // 128
#define XSP  68                // xs row stride (floats), padded vs 64
#define H1P  136               // h1c row stride (shorts), padded vs 128
#define XZP  516               // xzbuf row stride (floats), padded vs 512

using short8  = __attribute__((ext_vector_type(8))) short;   // 8 x bf16 (4 VGPRs)
using floatx4 = __attribute__((ext_vector_type(4))) float;   // MFMA C/D

// ---------- math helpers ----------
__device__ __forceinline__ float sigmoidf_(float x) {
    return __builtin_amdgcn_rcpf(1.0f + __expf(-x));
}
__device__ __forceinline__ float seluf_(float x) {
    const float a = 1.6732632423543772f;
    const float s = 1.0507009873554805f;
    return x > 0.0f ? s * x : s * a * (__expf(x) - 1.0f);
}
// fp32 -> bf16 bits, round-to-nearest-even
__device__ __forceinline__ unsigned short f2bf_(float f) {
    unsigned u = __float_as_uint(f);
    u += 0x7FFFu + ((u >> 16) & 1u);
    return (unsigned short)(u >> 16);
}

// ---------- fused two-layer LSTM, wavefront-pipelined ----------
// 128 blocks x 256 threads (4 waves -> 1 wave/SIMD; prev 8-wave version had
// 2 lockstep waves/SIMD doubling issue without filling barrier stalls).
// Each wave owns 32 output columns (2 groups of 16). U and W fragments stay
// resident in the unified VGPR/AGPR file (waves_per_eu(1,1) -> up to 512
// regs/wave; MFMA reads B operands from AGPR natively).
// Blocks [0,64):   layer 1, row b. Per chunk: xz1 = x@W1+b1 in LDS via MFMA,
//                  16 recurrent steps, publish bf16 h1 chunk via write-through
//                  relaxed agent atomics (coherent at IC, no wbl2), then flag.
//                  __syncthreads drains vmcnt(0) per wave => data stores
//                  complete at the coherence point before the flag store.
// Blocks [64,128): layer 2, row b. Polls flag (relaxed agent), stages h1 via
//                  relaxed agent atomic loads (cache-bypassing), builds
//                  xz2 = h1c@W2+b2 via MFMA, 16 rec steps, writes fp32 out.
__global__ __launch_bounds__(256)
__attribute__((amdgpu_waves_per_eu(1, 1)))
void fused_lstm(const float* __restrict__ x,                 // [B][T][64] fp32
                const float* __restrict__ W1,                // [64][512] fp32
                const float* __restrict__ U1,                // [128][512] fp32
                const float* __restrict__ b1,                // [512]
                const float* __restrict__ W2,                // [128][512] fp32
                const float* __restrict__ U2,
                const float* __restrict__ b2,
                unsigned long long* __restrict__ h1g,        // [B][T][128] bf16 (ws), u64 view
                unsigned* __restrict__ flags,                // [B] (zeroed by memset)
                float* __restrict__ out) {                   // [B][T][128] fp32
    const bool l2  = blockIdx.x >= BATCH;
    const int  b   = l2 ? ((int)blockIdx.x - BATCH) : (int)blockIdx.x;
    const int tid  = threadIdx.x;
    const int w    = tid >> 6;          // wave 0..3
    const int lane = tid & 63;
    const int c16  = lane & 15;
    const int quad = lane >> 4;
    const int j0   = w * 32 + c16;      // first owned column
    const int j1   = j0 + 16;           // second owned column

    __shared__ __align__(16) short hA[2][HID];           // bf16 h ping-pong
    __shared__ __align__(16) float xzbuf[CHUNK * XZP];   // fp32 z-pre, gate-interleaved, padded
    __shared__ __align__(16) float xs[CHUNK * XSP];      // l1: x chunk staged (padded)
    __shared__ __align__(16) short h1c[CHUNK * H1P];     // l2: h1 chunk staged (padded)
    __shared__ __align__(16) short h1buf[CHUNK * HID];   // l1: h chunk bf16 (flush buffer)
    __shared__ __align__(16) float hbuf[CHUNK * HID];    // l2: h chunk fp32 (out buffer)

    // ---- stage recurrent-weight fragments U (l1->U1, l2->U2), K=128, 2 col-groups ----
    const float* U = l2 ? U2 : U1;
    short8 bfrag[4][4][2];              // [kc][gate][grp]
#pragma unroll
    for (int g = 0; g < 4; ++g)
#pragma unroll
        for (int grp = 0; grp < 2; ++grp) {
            const float* Ucol = U + (size_t)(g * 128 + w * 32 + grp * 16 + c16);
#pragma unroll
            for (int kc = 0; kc < 4; ++kc) {
                short8 v;
#pragma unroll
                for (int jj = 0; jj < 8; ++jj) {
                    int k = kc * 32 + quad * 8 + jj;
                    v[jj] = (short)f2bf_(Ucol[(size_t)k * G4]);
                }
                bfrag[kc][g][grp] = v;
            }
        }

    // ---- stage input-projection fragments: l1 -> W1 (K=64, kc<2), l2 -> W2 (K=128) ----
    const float* Wp = l2 ? W2 : W1;
    const int KCW = l2 ? 4 : 2;
    short8 wfrag[4][4][2];              // [kc][gate][grp]; l1 kc>=2 dead
#pragma unroll
    for (int g = 0; g < 4; ++g)
#pragma unroll
        for (int grp = 0; grp < 2; ++grp) {
            const float* Wcol = Wp + (size_t)(g * 128 + w * 32 + grp * 16 + c16);
#pragma unroll
            for (int kc = 0; kc < 4; ++kc) {
                if (kc < KCW) {
                    short8 v;
#pragma unroll
                    for (int jj = 0; jj < 8; ++jj) {
                        int k = kc * 32 + quad * 8 + jj;
                        v[jj] = (short)f2bf_(Wcol[(size_t)k * G4]);
                    }
                    wfrag[kc][g][grp] = v;
                }
            }
        }
    const float* bb = l2 ? b2 : b1;
    const float4 biasA = make_float4(bb[j0], bb[128 + j0], bb[256 + j0], bb[384 + j0]);
    const float4 biasB = make_float4(bb[j1], bb[128 + j1], bb[256 + j1], bb[384 + j1]);

    const float* xb = x + (size_t)b * SEQT * FEAT;
    if (!l2) {   // prologue: stage x chunk 0 into padded LDS (256 float4)
        float4 v = ((const float4*)xb)[tid];
        *(float4*)&xs[(tid >> 4) * XSP + ((tid & 15) << 2)] = v;
    }
    if (tid < HID) hA[0][tid] = 0;      // h(-1) = 0
    float cst0 = 0.0f, cst1 = 0.0f;     // cell states for the 2 owned columns
    floatx4 zero4 = {0.f, 0.f, 0.f, 0.f};
    __syncthreads();

    float*              out_b = out + (size_t)b * SEQT * HID;
    unsigned long long* h1g_b = h1g + (size_t)b * (SEQT * HID / 4);  // 65536 u64/row

    for (int c = 0; c < NCHUNK; ++c) {
        float4 pf;
        if (!l2) {
            // prefetch next x chunk (4 KB, contiguous; in flight across chunk)
            if (c + 1 < NCHUNK)
                pf = ((const float4*)(xb + (size_t)(c + 1) * CHUNK * FEAT))[tid];
            // ---- build xz1 chunk: [16 t] x [512] = x_s @ W1 + b1, K=64 ----
            short8 ax[2];
#pragma unroll
            for (int kc = 0; kc < 2; ++kc) {
                const float* p = &xs[c16 * XSP + kc * 32 + quad * 8];
                float4 f0 = *(const float4*)p;
                float4 f1 = *(const float4*)(p + 4);
                short8 v;
                v[0] = (short)f2bf_(f0.x); v[1] = (short)f2bf_(f0.y);
                v[2] = (short)f2bf_(f0.z); v[3] = (short)f2bf_(f0.w);
                v[4] = (short)f2bf_(f1.x); v[5] = (short)f2bf_(f1.y);
                v[6] = (short)f2bf_(f1.z); v[7] = (short)f2bf_(f1.w);
                ax[kc] = v;
            }
            floatx4 acc1[4][2];
#pragma unroll
            for (int g = 0; g < 4; ++g)
#pragma unroll
                for (int grp = 0; grp < 2; ++grp) {
                    floatx4 t = __builtin_amdgcn_mfma_f32_16x16x32_bf16(ax[0], wfrag[0][g][grp], zero4, 0, 0, 0);
                    acc1[g][grp] = __builtin_amdgcn_mfma_f32_16x16x32_bf16(ax[1], wfrag[1][g][grp], t, 0, 0, 0);
                }
            // D mapping: col=lane&15, row=quad*4+reg (timestep)
#pragma unroll
            for (int r = 0; r < 4; ++r) {
                int srow = quad * 4 + r;
                *(float4*)&xzbuf[srow * XZP + j0 * 4] =
                    make_float4(acc1[0][0][r] + biasA.x, acc1[1][0][r] + biasA.y,
                                acc1[2][0][r] + biasA.z, acc1[3][0][r] + biasA.w);
                *(float4*)&xzbuf[srow * XZP + j1 * 4] =
                    make_float4(acc1[0][1][r] + biasB.x, acc1[1][1][r] + biasB.y,
                                acc1[2][1][r] + biasB.z, acc1[3][1][r] + biasB.w);
            }
            __syncthreads();
        } else {
            // ---- wait for layer-1 chunk c, then stage + build xz2 chunk ----
            if (tid == 0) {
                while (__hip_atomic_load(&flags[b], __ATOMIC_RELAXED,
                                         __HIP_MEMORY_SCOPE_AGENT) < (unsigned)(c + 1))
                    __builtin_amdgcn_s_sleep(2);
            }
            __syncthreads();
            // stage h1 chunk: 512 x 8B cache-bypassing loads (coherent at IC)
#pragma unroll
            for (int i = 0; i < 2; ++i) {
                int idx = tid + i * 256;
                unsigned long long hv = __hip_atomic_load(
                    h1g_b + (size_t)c * 512 + idx, __ATOMIC_RELAXED, __HIP_MEMORY_SCOPE_AGENT);
                *(unsigned long long*)&h1c[(idx >> 5) * H1P + (idx & 31) * 4] = hv;
            }
            __syncthreads();

            // xz2[t][n] = sum_k h1c[t][k] * W2[k][n] + b2  (M=16, K=128)
            short8 ah[4];
#pragma unroll
            for (int kc = 0; kc < 4; ++kc)
                ah[kc] = *(const short8*)&h1c[c16 * H1P + kc * 32 + quad * 8];
            floatx4 acc2[4][2];
#pragma unroll
            for (int g = 0; g < 4; ++g)
#pragma unroll
                for (int grp = 0; grp < 2; ++grp) {
                    floatx4 t = __builtin_amdgcn_mfma_f32_16x16x32_bf16(ah[0], wfrag[0][g][grp], zero4, 0, 0, 0);
                    t = __builtin_amdgcn_mfma_f32_16x16x32_bf16(ah[1], wfrag[1][g][grp], t, 0, 0, 0);
                    t = __builtin_amdgcn_mfma_f32_16x16x32_bf16(ah[2], wfrag[2][g][grp], t, 0, 0, 0);
                    acc2[g][grp] = __builtin_amdgcn_mfma_f32_16x16x32_bf16(ah[3], wfrag[3][g][grp], t, 0, 0, 0);
                }
#pragma unroll
            for (int r = 0; r < 4; ++r) {
                int srow = quad * 4 + r;
                *(float4*)&xzbuf[srow * XZP + j0 * 4] =
                    make_float4(acc2[0][0][r] + biasA.x, acc2[1][0][r] + biasA.y,
                                acc2[2][0][r] + biasA.z, acc2[3][0][r] + biasA.w);
                *(float4*)&xzbuf[srow * XZP + j1 * 4] =
                    make_float4(acc2[0][1][r] + biasB.x, acc2[1][1][r] + biasB.y,
                                acc2[2][1][r] + biasB.z, acc2[3][1][r] + biasB.w);
            }
            __syncthreads();
        }

        // ---- 16 recurrent steps ----
#pragma unroll 2
        for (int s = 0; s < CHUNK; ++s) {
            const short* hb = &hA[s & 1][0];
            short8 af[4];
#pragma unroll
            for (int kc = 0; kc < 4; ++kc)
                af[kc] = *(const short8*)&hb[kc * 32 + quad * 8];
            float4 xqA = *(const float4*)&xzbuf[s * XZP + j0 * 4];
            float4 xqB = *(const float4*)&xzbuf[s * XZP + j1 * 4];

            // two 2-deep chains per (gate,grp) instead of one 4-deep chain
            floatx4 accA[4][2], accB[4][2];
#pragma unroll
            for (int g = 0; g < 4; ++g)
#pragma unroll
                for (int grp = 0; grp < 2; ++grp) {
                    floatx4 t0 = __builtin_amdgcn_mfma_f32_16x16x32_bf16(af[0], bfrag[0][g][grp], zero4, 0, 0, 0);
                    accA[g][grp] = __builtin_amdgcn_mfma_f32_16x16x32_bf16(af[1], bfrag[1][g][grp], t0, 0, 0, 0);
                    floatx4 t1 = __builtin_amdgcn_mfma_f32_16x16x32_bf16(af[2], bfrag[2][g][grp], zero4, 0, 0, 0);
                    accB[g][grp] = __builtin_amdgcn_mfma_f32_16x16x32_bf16(af[3], bfrag[3][g][grp], t1, 0, 0, 0);
                }

            float h0, h1f;
            unsigned short h0b, h1b;
            {
                float zi = accA[0][0][0] + accB[0][0][0] + xqA.x;
                float zf = accA[1][0][0] + accB[1][0][0] + xqA.y;
                float zg = accA[2][0][0] + accB[2][0][0] + xqA.z;
                float zo = accA[3][0][0] + accB[3][0][0] + xqA.w;
                float ig = sigmoidf_(zi), fg = sigmoidf_(zf);
                float gg = seluf_(zg),   og = sigmoidf_(zo);
                cst0 = fg * cst0 + ig * gg;
                h0 = og * seluf_(cst0);
                h0b = f2bf_(h0);
            }
            {
                float zi = accA[0][1][0] + accB[0][1][0] + xqB.x;
                float zf = accA[1][1][0] + accB[1][1][0] + xqB.y;
                float zg = accA[2][1][0] + accB[2][1][0] + xqB.z;
                float zo = accA[3][1][0] + accB[3][1][0] + xqB.w;
                float ig = sigmoidf_(zi), fg = sigmoidf_(zf);
                float gg = seluf_(zg),   og = sigmoidf_(zo);
                cst1 = fg * cst1 + ig * gg;
                h1f = og * seluf_(cst1);
                h1b = f2bf_(h1f);
            }

            if (lane < 32) {                 // lanes 0..31 cover cols w*32..w*32+31
                int col = w * 32 + lane;
                unsigned short hv = (lane < 16) ? h0b : h1b;
                hA[(s + 1) & 1][col] = (short)hv;
                if (l2) hbuf[s * HID + col] = (lane < 16) ? h0 : h1f;
                else    h1buf[s * HID + col] = (short)hv;
            }
            __syncthreads();
        }

        // ---- chunk boundary ----
        if (!l2) {
            // flush h1 chunk: 512 x 8B write-through stores (coherent at IC)
#pragma unroll
            for (int i = 0; i < 2; ++i) {
                int idx = tid + i * 256;
                unsigned long long hv = *(const unsigned long long*)&h1buf[idx * 4];
                __hip_atomic_store(h1g_b + (size_t)c * 512 + idx, hv,
                                   __ATOMIC_RELAXED, __HIP_MEMORY_SCOPE_AGENT);
            }
            // install prefetched x chunk
            if (c + 1 < NCHUNK)
                *(float4*)&xs[(tid >> 4) * XSP + ((tid & 15) << 2)] = pf;
            __syncthreads();   // per-wave vmcnt(0) drain: h1 stores reached IC
            if (tid == 0)
                __hip_atomic_store(&flags[b], (unsigned)(c + 1),
                                   __ATOMIC_RELAXED, __HIP_MEMORY_SCOPE_AGENT);
        } else {
#pragma unroll
            for (int i = 0; i < 2; ++i) {
                int idx = tid + i * 256;
                *(float4*)&out_b[(size_t)c * CHUNK * HID + idx * 4] =
                    *(const float4*)&hbuf[idx * 4];
            }
            // next chunk's spin+syncthreads protects hbuf reuse
        }
    }
}

// ---------- host launch ----------
// ws layout:
//   [0, 32 MB)        h1 bf16  (layer-1 -> layer-2 pipe, IC-coherent atomics)
//   [32 MB, +256 B)   per-row chunk flags (zeroed via memsetAsync each call)
extern "C" void kernel_launch(void* const* d_in, const int* in_sizes, int n_in,
                              void* d_out, int out_size, void* d_ws, size_t ws_size,
                              hipStream_t stream) {
    const float* x  = (const float*)d_in[0];
    const float* W1 = (const float*)d_in[1];
    const float* U1 = (const float*)d_in[2];
    const float* b1 = (const float*)d_in[3];
    const float* W2 = (const float*)d_in[4];
    const float* U2 = (const float*)d_in[5];
    const float* b2 = (const float*)d_in[6];
    float* out = (float*)d_out;

    const size_t BT       = (size_t)BATCH * SEQT;
    const size_t H1_BYTES = BT * HID * 2;    // 32 MB

    unsigned long long* h1g   = (unsigned long long*)d_ws;
    unsigned*           flags = (unsigned*)((char*)d_ws + H1_BYTES);

    hipMemsetAsync(flags, 0, BATCH * sizeof(unsigned), stream);

    fused_lstm<<<dim3(2 * BATCH), dim3(256), 0, stream>>>(
        x, W1, U1, b1, W2, U2, b2, h1g, flags, out);
}